// Round 4
// baseline (437.935 us; speedup 1.0000x reference)
//
#include <hip/hip_runtime.h>
#include <hip/hip_bf16.h>

// B=1024, N(nodes)=128, H=128, D=8
// out = [f_out (B*N)] ++ [g_out (B*N*D)], fp32
//
// R4: single fused kernel. Per block: node i = bx&127 (XCD-affine), 256 rows of x.
// B-tile (64 combined cols x 128 n) transposed fp32->bf16 in-kernel into swizzled,
// double-buffered LDS (conflict-free ds_write_b128). A (x * log2e) register-resident
// as bf16 fragments. ELU epilogue in scaled domain:
//   elu(t)*w = (max(u,0)*ln2 + exp2(min(u,0)))*w - w,  u = t*log2e
// accumulated without the -1; per-lane-subset sum(w) subtracted once at writeout.

typedef unsigned short u16;
typedef __attribute__((ext_vector_type(8))) short bf16x8;
typedef __attribute__((ext_vector_type(4))) float f32x4;

#define LOG2E 1.4426950408889634f
#define LN2   0.6931471805599453f

__device__ __forceinline__ uint32_t pk2(float a, float b) {
    __hip_bfloat162 h = __float22bfloat162_rn(make_float2(a, b));
    union { __hip_bfloat162 h2; uint32_t u; } c;
    c.h2 = h;
    return c.u;
}

// p += (max(u,0)*ln2 + exp2(min(u,0))) * wv   (elu contribution, missing -wv)
__device__ __forceinline__ float elu_acc(float u, float wv, float p) {
    float m = fmaxf(u, 0.f);
    float e = __builtin_amdgcn_exp2f(fminf(u, 0.f));
    return fmaf(fmaf(m, LN2, e), wv, p);
}

// grid 512 = 128 nodes x 4 row-tiles(256); block 256 (4 waves, rows split 4x1, 64 rows/wave)
__global__ __launch_bounds__(256, 2) void sde_fused(
    const float* __restrict__ x, const float* __restrict__ fw, const float* __restrict__ gw,
    const float* __restrict__ Wf, const float* __restrict__ bfp,
    const float* __restrict__ Wg, const float* __restrict__ bgp,
    float* __restrict__ out)
{
    // Swizzled tile: row c (0..63), 16-byte chunk j (0..15) stored at chunk j^(c&7).
    __shared__ u16 wst[2][64 * 128];   // 2 x 16 KB
    __shared__ float wgs[128];
    __shared__ float wfs[128];

    const int t = threadIdx.x, bx = blockIdx.x;
    const int i    = bx & 127;          // same-node blocks co-XCD (bx%8 == i%8)
    const int b0   = (bx >> 7) << 8;    // 256-row tile base
    const int w    = t >> 6;
    const int lane = t & 63;
    const int l15  = lane & 15;
    const int quad = lane >> 4;
    const int l31  = lane & 31;
    const int jj   = lane >> 5;
    const int c0   = l31 * 2;           // local col pair base
    const int sw   = l15 & 7;

    if (t < 128) { wgs[t] = Wg[i * 128 + t]; wfs[t] = Wf[i * 128 + t]; }

    // ---- A fragments: x * log2e -> bf16, rows w*64 + ms*16 + l15, k = quad*8 + kk*32 ----
    bf16x8 afr[4][4];
    #pragma unroll
    for (int ms = 0; ms < 4; ++ms) {
        const float* xr = x + (size_t)(b0 + w * 64 + ms * 16 + l15) * 128 + quad * 8;
        #pragma unroll
        for (int kk = 0; kk < 4; ++kk) {
            float4 v0 = *(const float4*)(xr + kk * 32);
            float4 v1 = *(const float4*)(xr + kk * 32 + 4);
            union { uint32_t u[4]; bf16x8 v; } r;
            r.u[0] = pk2(v0.x * LOG2E, v0.y * LOG2E);
            r.u[1] = pk2(v0.z * LOG2E, v0.w * LOG2E);
            r.u[2] = pk2(v1.x * LOG2E, v1.y * LOG2E);
            r.u[3] = pk2(v1.z * LOG2E, v1.w * LOG2E);
            afr[ms][kk] = r.v;
        }
    }

    const float* gwi = gw + (size_t)i * 131072;
    const float* fwi = fw + (size_t)i * 16384;

    // ---- staging: per wave 4 n-chunks (j = w*4 + it*2 + jj), cols c0,c0+1 ----
    float2 vr[2][8];
    auto load_tile = [&](int ct) {
        const float* src;
        int rstride;
        if (ct < 16) { src = gwi + ct * 64;        rstride = 1024; }
        else         { src = fwi + (ct - 16) * 64; rstride = 128;  }
        #pragma unroll
        for (int it = 0; it < 2; ++it) {
            const int j = w * 4 + it * 2 + jj;
            const float* s2 = src + (size_t)(8 * j) * rstride + c0;
            #pragma unroll
            for (int r = 0; r < 8; ++r)
                vr[it][r] = *(const float2*)(s2 + (size_t)r * rstride);
        }
    };
    auto write_tile = [&](int p) {
        #pragma unroll
        for (int it = 0; it < 2; ++it) {
            const int j = w * 4 + it * 2 + jj;
            {
                const int c = c0;
                union { uint32_t u[4]; bf16x8 v; } rr;
                rr.u[0] = pk2(vr[it][0].x, vr[it][1].x);
                rr.u[1] = pk2(vr[it][2].x, vr[it][3].x);
                rr.u[2] = pk2(vr[it][4].x, vr[it][5].x);
                rr.u[3] = pk2(vr[it][6].x, vr[it][7].x);
                *(bf16x8*)&wst[p][c * 128 + ((j ^ (c & 7)) << 3)] = rr.v;
            }
            {
                const int c = c0 + 1;
                union { uint32_t u[4]; bf16x8 v; } rr;
                rr.u[0] = pk2(vr[it][0].y, vr[it][1].y);
                rr.u[1] = pk2(vr[it][2].y, vr[it][3].y);
                rr.u[2] = pk2(vr[it][4].y, vr[it][5].y);
                rr.u[3] = pk2(vr[it][6].y, vr[it][7].y);
                *(bf16x8*)&wst[p][c * 128 + ((j ^ (c & 7)) << 3)] = rr.v;
            }
        }
    };

    float racc[16], frac[16];
    #pragma unroll
    for (int q = 0; q < 16; ++q) { racc[q] = 0.f; frac[q] = 0.f; }

    load_tile(0);
    write_tile(0);
    __syncthreads();

    int p = 0;
    for (int ct = 0; ct < 18; ++ct) {
        if (ct < 17) load_tile(ct + 1);   // regs for next tile, latency hidden by compute

        f32x4 acc[4][4];
        #pragma unroll
        for (int ms = 0; ms < 4; ++ms)
            #pragma unroll
            for (int cs = 0; cs < 4; ++cs)
                acc[ms][cs] = (f32x4){0.f, 0.f, 0.f, 0.f};

        #pragma unroll
        for (int kk = 0; kk < 4; ++kk) {
            const int co = ((kk * 4 + quad) ^ sw) << 3;
            bf16x8 bv[4];
            #pragma unroll
            for (int cs = 0; cs < 4; ++cs)
                bv[cs] = *(const bf16x8*)&wst[p][(cs * 16 + l15) * 128 + co];
            #pragma unroll
            for (int ms = 0; ms < 4; ++ms)
                #pragma unroll
                for (int cs = 0; cs < 4; ++cs)
                    acc[ms][cs] = __builtin_amdgcn_mfma_f32_16x16x32_bf16(afr[ms][kk], bv[cs], acc[ms][cs], 0, 0, 0);
        }

        // fused epilogue; C/D layout col=l15, row=quad*4+reg
        if (ct < 16) {
            // g: C = ct*64+cs*16+l15 = h*8+d -> d=l15&7, h = ct*8 + cs*2 + (l15>>3)
            float wv[4];
            #pragma unroll
            for (int cs = 0; cs < 4; ++cs) wv[cs] = wgs[ct * 8 + cs * 2 + (l15 >> 3)];
            #pragma unroll
            for (int ms = 0; ms < 4; ++ms)
                #pragma unroll
                for (int rg = 0; rg < 4; ++rg) {
                    float s = racc[ms * 4 + rg];
                    s = elu_acc(acc[ms][0][rg], wv[0], s);
                    s = elu_acc(acc[ms][1][rg], wv[1], s);
                    s = elu_acc(acc[ms][2][rg], wv[2], s);
                    s = elu_acc(acc[ms][3][rg], wv[3], s);
                    racc[ms * 4 + rg] = s;
                }
        } else {
            // f: h = (ct-16)*64 + cs*16 + l15
            float wv[4];
            #pragma unroll
            for (int cs = 0; cs < 4; ++cs) wv[cs] = wfs[(ct - 16) * 64 + cs * 16 + l15];
            #pragma unroll
            for (int ms = 0; ms < 4; ++ms)
                #pragma unroll
                for (int rg = 0; rg < 4; ++rg) {
                    float s = frac[ms * 4 + rg];
                    s = elu_acc(acc[ms][0][rg], wv[0], s);
                    s = elu_acc(acc[ms][1][rg], wv[1], s);
                    s = elu_acc(acc[ms][2][rg], wv[2], s);
                    s = elu_acc(acc[ms][3][rg], wv[3], s);
                    frac[ms * 4 + rg] = s;
                }
        }

        if (ct < 17) {
            write_tile(p ^ 1);
            __syncthreads();
            p ^= 1;
        }
    }

    // ---- corrections (the deferred -sum(w) over each lane's h-subset) ----
    float Sg = 0.f, Sf = 0.f;
    {
        const int hb = l15 >> 3;
        #pragma unroll 8
        for (int h = 0; h < 128; h += 2) Sg += wgs[h + hb];
        #pragma unroll
        for (int h = 0; h < 128; h += 16) Sf += wfs[h + l15];
    }

    // ---- reductions + writeout ----
    const float bfv = bfp[i], bgv = bgp[i];
    #pragma unroll
    for (int ms = 0; ms < 4; ++ms)
        #pragma unroll
        for (int rg = 0; rg < 4; ++rg) {
            const int q = ms * 4 + rg;
            float g = racc[q] - Sg;
            g += __shfl_xor(g, 8);             // combine h-parity halves (same d=l15&7)
            float f = frac[q] - Sf;
            f += __shfl_xor(f, 1);
            f += __shfl_xor(f, 2);
            f += __shfl_xor(f, 4);
            f += __shfl_xor(f, 8);
            const int row = w * 64 + ms * 16 + quad * 4 + rg;
            const size_t brow = (size_t)(b0 + row);
            if (l15 == 0)
                out[brow * 128 + i] = f + bfv;
            if (l15 < 8)
                out[(size_t)131072 + (brow * 128 + i) * 8 + (lane & 7)] = g + bgv;
        }
}

extern "C" void kernel_launch(void* const* d_in, const int* in_sizes, int n_in,
                              void* d_out, int out_size, void* d_ws, size_t ws_size,
                              hipStream_t stream) {
    const float* x  = (const float*)d_in[0];
    const float* fw = (const float*)d_in[1];
    const float* gw = (const float*)d_in[2];
    const float* Wf = (const float*)d_in[3];
    const float* bf = (const float*)d_in[4];
    const float* Wg = (const float*)d_in[5];
    const float* bg = (const float*)d_in[6];
    float* out = (float*)d_out;
    (void)d_ws; (void)ws_size;

    sde_fused<<<512, 256, 0, stream>>>(x, fw, gw, Wf, bf, Wg, bg, out);
}

// Round 5
// 177.506 us; speedup vs baseline: 2.4672x; 2.4672x over previous
//
#include <hip/hip_runtime.h>
#include <hip/hip_bf16.h>

// B=1024, N(nodes)=128, H=128, D=8
// out = [f_out (B*N)] ++ [g_out (B*N*D)], fp32
//
// R5: fused single kernel, M=128 rows/block (grid 1024 = 8 row-tiles x 128 nodes,
// i = bx&127 so same-node blocks share an XCD's L2). Per ct (18 tiles of 64 combined
// cols), the block transposes+converts the fp32 weight tile into swizzled double-
// buffered LDS (half-tile pipeline, one barrier/iter, loads consumed pre-barrier).
// A = x*log2e register-resident bf16. Scaled-domain ELU epilogue:
//   elu(t)*w = (max(u,0)*ln2 + exp2(min(u,0)))*w - w,  u = t*log2e
// accumulated without -w; sum(w) subtracted at writeout. f-tiles (ct=16,17) first so
// the f accumulator folds into racc and f_out stores early.

typedef unsigned short u16;
typedef __attribute__((ext_vector_type(8))) short bf16x8;
typedef __attribute__((ext_vector_type(4))) float f32x4;

#define LOG2E 1.4426950408889634f
#define LN2   0.6931471805599453f

__device__ __forceinline__ uint32_t pk2(float a, float b) {
    union { __hip_bfloat162 h2; uint32_t u; } c;
    c.h2 = __float22bfloat162_rn(make_float2(a, b));
    return c.u;
}
// p += (max(u,0)*ln2 + exp2(min(u,0))) * wv   (elu contribution, missing -wv)
__device__ __forceinline__ float elu_acc(float u, float wv, float p) {
    float m = fmaxf(u, 0.f);
    float e = __builtin_amdgcn_exp2f(fminf(u, 0.f));
    return fmaf(fmaf(m, LN2, e), wv, p);
}

__global__ __launch_bounds__(256, 4) void sde_fused(
    const float* __restrict__ x, const float* __restrict__ fw, const float* __restrict__ gw,
    const float* __restrict__ Wf, const float* __restrict__ bfp,
    const float* __restrict__ Wg, const float* __restrict__ bgp,
    float* __restrict__ out)
{
    // Swizzled tile: row c (0..63), 16B chunk j (0..15) stored at chunk j ^ ((c>>1)&7).
    __shared__ u16 wst[2][64 * 128];   // 2 x 16 KB
    __shared__ float wgs[128];
    __shared__ float wfs[128];

    const int t = threadIdx.x, bx = blockIdx.x;
    const int i    = bx & 127;          // same-node blocks co-XCD (bx%8 == i%8)
    const int b0   = (bx >> 7) << 7;    // 128-row tile base
    const int w    = t >> 6;
    const int lane = t & 63;
    const int l15  = lane & 15;
    const int quad = lane >> 4;
    const int l31  = lane & 31;
    const int jj   = lane >> 5;
    const int c0   = l31 * 2;           // staged col pair base
    const int sw   = (l15 >> 1) & 7;    // read-side swizzle

    if (t < 128) { wgs[t] = Wg[i * 128 + t]; wfs[t] = Wf[i * 128 + t]; }

    // ---- A fragments: x * log2e -> bf16, rows w*32 + rs*16 + l15, k = quad*8 + kk*32 ----
    bf16x8 afr[2][4];
    #pragma unroll
    for (int rs = 0; rs < 2; ++rs) {
        const float* xr = x + (size_t)(b0 + w * 32 + rs * 16 + l15) * 128 + quad * 8;
        #pragma unroll
        for (int kk = 0; kk < 4; ++kk) {
            float4 v0 = *(const float4*)(xr + kk * 32);
            float4 v1 = *(const float4*)(xr + kk * 32 + 4);
            union { uint32_t u[4]; bf16x8 v; } r;
            r.u[0] = pk2(v0.x * LOG2E, v0.y * LOG2E);
            r.u[1] = pk2(v0.z * LOG2E, v0.w * LOG2E);
            r.u[2] = pk2(v1.x * LOG2E, v1.y * LOG2E);
            r.u[3] = pk2(v1.z * LOG2E, v1.w * LOG2E);
            afr[rs][kk] = r.v;
        }
    }

    const float* gwi = gw + (size_t)i * 131072;
    const float* fwi = fw + (size_t)i * 16384;

    // ---- staging: half = 8 n-octets; this thread covers j = half*8 + w*2 + jj, cols c0,c0+1 ----
    float2 vr[8];
    auto load_half = [&](int ct, int half) {
        const float* src; int rstride;
        if (ct < 16) { src = gwi + ct * 64;        rstride = 1024; }
        else         { src = fwi + (ct - 16) * 64; rstride = 128;  }
        const int j = half * 8 + w * 2 + jj;
        const float* s2 = src + (size_t)(8 * j) * rstride + c0;
        #pragma unroll
        for (int r = 0; r < 8; ++r) vr[r] = *(const float2*)(s2 + (size_t)r * rstride);
    };
    auto write_half = [&](int p, int half) {
        const int j = half * 8 + w * 2 + jj;
        const int slot = (j ^ (l31 & 7)) << 3;       // (c0>>1)&7 == l31&7 for both cols
        union { uint32_t u[4]; bf16x8 v; } rr;
        rr.u[0] = pk2(vr[0].x, vr[1].x); rr.u[1] = pk2(vr[2].x, vr[3].x);
        rr.u[2] = pk2(vr[4].x, vr[5].x); rr.u[3] = pk2(vr[6].x, vr[7].x);
        *(bf16x8*)&wst[p][c0 * 128 + slot] = rr.v;
        rr.u[0] = pk2(vr[0].y, vr[1].y); rr.u[1] = pk2(vr[2].y, vr[3].y);
        rr.u[2] = pk2(vr[4].y, vr[5].y); rr.u[3] = pk2(vr[6].y, vr[7].y);
        *(bf16x8*)&wst[p][(c0 + 1) * 128 + slot] = rr.v;
    };

    // prologue: stage ct=16 (first f-tile) into buffer 0
    load_half(16, 0); write_half(0, 0);
    load_half(16, 1); write_half(0, 1);
    __syncthreads();

    float racc[8];
    #pragma unroll
    for (int q = 0; q < 8; ++q) racc[q] = 0.f;
    const float bfv = bfp[i], bgv = bgp[i];

    int p = 0;
    for (int idx = 0; idx < 18; ++idx) {
        const int ct  = (idx < 2) ? 16 + idx : idx - 2;   // order: 16,17,0..15
        const bool pre = idx < 17;
        const int ctn = (idx == 0) ? 17 : idx - 1;        // next tile's ct

        f32x4 acc[2][4];
        #pragma unroll
        for (int rs = 0; rs < 2; ++rs)
            #pragma unroll
            for (int cs = 0; cs < 4; ++cs)
                acc[rs][cs] = (f32x4){0.f, 0.f, 0.f, 0.f};

        if (pre) load_half(ctn, 0);

        #pragma unroll
        for (int kk = 0; kk < 2; ++kk) {
            const int co = ((kk * 4 + quad) ^ sw) << 3;
            bf16x8 bv[4];
            #pragma unroll
            for (int cs = 0; cs < 4; ++cs)
                bv[cs] = *(const bf16x8*)&wst[p][(cs * 16 + l15) * 128 + co];
            #pragma unroll
            for (int cs = 0; cs < 4; ++cs) {
                acc[0][cs] = __builtin_amdgcn_mfma_f32_16x16x32_bf16(afr[0][kk], bv[cs], acc[0][cs], 0, 0, 0);
                acc[1][cs] = __builtin_amdgcn_mfma_f32_16x16x32_bf16(afr[1][kk], bv[cs], acc[1][cs], 0, 0, 0);
            }
        }

        if (pre) { write_half(p ^ 1, 0); load_half(ctn, 1); }

        #pragma unroll
        for (int kk = 2; kk < 4; ++kk) {
            const int co = ((kk * 4 + quad) ^ sw) << 3;
            bf16x8 bv[4];
            #pragma unroll
            for (int cs = 0; cs < 4; ++cs)
                bv[cs] = *(const bf16x8*)&wst[p][(cs * 16 + l15) * 128 + co];
            #pragma unroll
            for (int cs = 0; cs < 4; ++cs) {
                acc[0][cs] = __builtin_amdgcn_mfma_f32_16x16x32_bf16(afr[0][kk], bv[cs], acc[0][cs], 0, 0, 0);
                acc[1][cs] = __builtin_amdgcn_mfma_f32_16x16x32_bf16(afr[1][kk], bv[cs], acc[1][cs], 0, 0, 0);
            }
        }

        // fused epilogue; C/D layout col=l15, row=quad*4+reg
        if (idx < 2) {
            // f: h = (ct-16)*64 + cs*16 + l15
            float wv[4];
            #pragma unroll
            for (int cs = 0; cs < 4; ++cs) wv[cs] = wfs[(ct - 16) * 64 + cs * 16 + l15];
            #pragma unroll
            for (int rs = 0; rs < 2; ++rs)
                #pragma unroll
                for (int rg = 0; rg < 4; ++rg) {
                    float s = racc[rs * 4 + rg];
                    s = elu_acc(acc[rs][0][rg], wv[0], s);
                    s = elu_acc(acc[rs][1][rg], wv[1], s);
                    s = elu_acc(acc[rs][2][rg], wv[2], s);
                    s = elu_acc(acc[rs][3][rg], wv[3], s);
                    racc[rs * 4 + rg] = s;
                }
        } else {
            // g: C = ct*64+cs*16+l15 = h*8+d -> d=l15&7, h = ct*8 + cs*2 + (l15>>3)
            float wv[4];
            #pragma unroll
            for (int cs = 0; cs < 4; ++cs) wv[cs] = wgs[ct * 8 + cs * 2 + (l15 >> 3)];
            #pragma unroll
            for (int rs = 0; rs < 2; ++rs)
                #pragma unroll
                for (int rg = 0; rg < 4; ++rg) {
                    float s = racc[rs * 4 + rg];
                    s = elu_acc(acc[rs][0][rg], wv[0], s);
                    s = elu_acc(acc[rs][1][rg], wv[1], s);
                    s = elu_acc(acc[rs][2][rg], wv[2], s);
                    s = elu_acc(acc[rs][3][rg], wv[3], s);
                    racc[rs * 4 + rg] = s;
                }
        }

        if (pre) write_half(p ^ 1, 1);

        if (idx == 1) {
            // f writeout (after ct=16,17): subtract per-lane sum(wf), 16-lane reduce, store, reset
            float Sf = 0.f;
            #pragma unroll
            for (int jh = 0; jh < 8; ++jh) Sf += wfs[jh * 16 + l15];
            #pragma unroll
            for (int rs = 0; rs < 2; ++rs)
                #pragma unroll
                for (int rg = 0; rg < 4; ++rg) {
                    float f = racc[rs * 4 + rg] - Sf;
                    f += __shfl_xor(f, 1);
                    f += __shfl_xor(f, 2);
                    f += __shfl_xor(f, 4);
                    f += __shfl_xor(f, 8);
                    if (l15 == 0) {
                        const int row = w * 32 + rs * 16 + quad * 4 + rg;
                        out[(size_t)(b0 + row) * 128 + i] = f + bfv;
                    }
                    racc[rs * 4 + rg] = 0.f;
                }
        }

        if (pre) __syncthreads();
        p ^= 1;
    }

    // ---- g writeout: subtract per-lane sum(wg) over its h-parity, pair-reduce, store ----
    float Sg = 0.f;
    {
        const int hb = l15 >> 3;
        #pragma unroll 8
        for (int h = 0; h < 128; h += 2) Sg += wgs[h + hb];
    }
    #pragma unroll
    for (int rs = 0; rs < 2; ++rs)
        #pragma unroll
        for (int rg = 0; rg < 4; ++rg) {
            float g = racc[rs * 4 + rg] - Sg;
            g += __shfl_xor(g, 8);             // combine h-parity halves (same d = l15&7)
            if (l15 < 8) {
                const int row = w * 32 + rs * 16 + quad * 4 + rg;
                out[(size_t)131072 + ((size_t)(b0 + row) * 128 + i) * 8 + (lane & 7)] = g + bgv;
            }
        }
}

extern "C" void kernel_launch(void* const* d_in, const int* in_sizes, int n_in,
                              void* d_out, int out_size, void* d_ws, size_t ws_size,
                              hipStream_t stream) {
    const float* x  = (const float*)d_in[0];
    const float* fw = (const float*)d_in[1];
    const float* gw = (const float*)d_in[2];
    const float* Wf = (const float*)d_in[3];
    const float* bf = (const float*)d_in[4];
    const float* Wg = (const float*)d_in[5];
    const float* bg = (const float*)d_in[6];
    float* out = (float*)d_out;
    (void)d_ws; (void)ws_size;

    sde_fused<<<1024, 256, 0, stream>>>(x, fw, gw, Wf, bf, Wg, bg, out);
}